// Round 4
// baseline (1041.370 us; speedup 1.0000x reference)
//
#include <hip/hip_runtime.h>
#include <hip/hip_bf16.h>

namespace {

constexpr int S_LEN  = 2048;
constexpr int DH     = 128;
constexpr int NG     = 16;     // global tokens
constexpr int HALF_W = 256;    // WINDOW/2
constexpr int TQ     = 64;     // q rows per workgroup
constexpr int TK     = 32;     // keys per tile
constexpr int NT     = S_LEN / TK;  // 64
constexpr int BH     = 32;     // B*H

typedef __attribute__((ext_vector_type(8))) short bf16x8;
typedef __attribute__((ext_vector_type(4))) float f32x4;

// hi = truncation to bf16 (1 op); residual returned for the lo part.
__device__ __forceinline__ unsigned short bfhi(float x, float& rem) {
  unsigned b = __builtin_bit_cast(unsigned, x);
  unsigned short h = (unsigned short)(b >> 16);
  rem = x - __builtin_bit_cast(float, (unsigned)h << 16);
  return h;
}
// plain truncation (for the residual; error ~2^-16 relative overall)
__device__ __forceinline__ unsigned short bftr(float x) {
  return (unsigned short)(__builtin_bit_cast(unsigned, x) >> 16);
}
// round-half-up to bf16 (2 ops; error <= 2^-9 rel) — for V and P
__device__ __forceinline__ unsigned short bfrn(float x) {
  return (unsigned short)((__builtin_bit_cast(unsigned, x) + 0x8000u) >> 16);
}

__global__ __launch_bounds__(256, 3)
void gla_fwd(const float* __restrict__ Q, const float* __restrict__ K,
             const float* __restrict__ V, float* __restrict__ O)
{
  __shared__ unsigned short khi[TK * DH];       // 8 KB
  __shared__ unsigned short klo[TK * DH];       // 8 KB
  __shared__ unsigned short plds[4 * 16 * TK];  // 4 KB (1 KB per wave)

  const int tid  = threadIdx.x;
  const int w    = tid >> 6;
  const int l    = tid & 63;
  const int lo16 = l & 15;
  const int g    = l >> 4;

  // XCD-aware block swizzle (1024 % 8 == 0 -> bijective)
  const int nwg  = BH * (S_LEN / TQ);          // 1024
  const int cpx  = nwg >> 3;                   // 128
  const int bsw  = (blockIdx.x & 7) * cpx + (blockIdx.x >> 3);

  const int bh = bsw >> 5;            // 0..31
  const int i0 = (bsw & 31) * TQ;     // q row-tile base
  const int qb = i0 + w * 16;         // this wave's q base

  const size_t base = (size_t)bh * S_LEN * DH;
  const float* Qb = Q + base;
  const float* Kb = K + base;
  const float* Vb = V + base;
  float*       Ob = O + base;

  // ---- Q fragments: scaled, hi/lo split. A-frag: lane holds Q[qb+lo16][32c+8g+j]
  bf16x8 qhi[4], qlo[4];
  {
    const float scale = 0.08838834764831845f;  // 1/sqrt(128)
    const float* qp = Qb + (size_t)(qb + lo16) * DH + g * 8;
#pragma unroll
    for (int c = 0; c < 4; ++c) {
      float4 a = *(const float4*)(qp + c * 32);
      float4 b = *(const float4*)(qp + c * 32 + 4);
      float xs[8] = {a.x, a.y, a.z, a.w, b.x, b.y, b.z, b.w};
#pragma unroll
      for (int j = 0; j < 8; ++j) {
        float x = xs[j] * scale, r;
        qhi[c][j] = (short)bfhi(x, r);
        qlo[c][j] = (short)bftr(r);
      }
    }
  }

  const f32x4 zero4 = {0.f, 0.f, 0.f, 0.f};
  f32x4 accO[8];
#pragma unroll
  for (int dt = 0; dt < 8; ++dt) accO[dt] = zero4;
  float mrow[4] = {-1e30f, -1e30f, -1e30f, -1e30f};
  float lrow[4] = {0.f, 0.f, 0.f, 0.f};

  int t_lo = (i0 - HALF_W) >> 5; if (t_lo < 0) t_lo = 0;
  int t_hi = (i0 + TQ - 1 + HALF_W) >> 5;
  if (i0 == 0) t_hi = NT - 1;               // global rows see everything
  if (t_hi > NT - 1) t_hi = NT - 1;
  const int tstart = (t_lo > 1) ? t_lo : 1; // tile 0 handled explicitly

  // ---- T14 async-STAGE: K tile for iteration ti is loaded to regs during ti-1
  float4 kreg[4];
  auto load_ktile = [&](int kt) {
#pragma unroll
    for (int i = 0; i < 4; ++i) {
      const int e   = (i * 256 + tid) * 4;
      const int row = e >> 7;
      const int d   = e & 127;
      kreg[i] = *(const float4*)(Kb + (size_t)(kt + row) * DH + d);
    }
  };
  load_ktile(0);   // prologue: tile 0

  for (int ti = 0;; ++ti) {
    const int t = (ti == 0) ? 0 : (tstart + ti - 1);
    if (ti > 0 && t > t_hi) break;
    const int kt = t * TK;

    __syncthreads();   // all waves done reading previous LDS tile
    // ---- cvt + write staged regs -> LDS bf16 hi/lo, XOR-swizzled ----
#pragma unroll
    for (int i = 0; i < 4; ++i) {
      const int e   = (i * 256 + tid) * 4;
      const int row = e >> 7;
      const int d   = e & 127;
      float4 f = kreg[i];
      ushort4 hv, lv;
      float r;
      hv.x = bfhi(f.x, r); lv.x = bftr(r);
      hv.y = bfhi(f.y, r); lv.y = bftr(r);
      hv.z = bfhi(f.z, r); lv.z = bftr(r);
      hv.w = bfhi(f.w, r); lv.w = bftr(r);
      const int byte = (row * 256 + d * 2) ^ ((row & 7) << 4);
      *(ushort4*)((char*)khi + byte) = hv;
      *(ushort4*)((char*)klo + byte) = lv;
    }
    __syncthreads();   // tile t visible to all waves

    // per-wave activity for this tile (compute BEFORE issuing loads)
    const bool wave_active =
        ((kt + TK - 1 >= qb - HALF_W) && (kt <= qb + 15 + HALF_W)) ||
        (t == 0) || (qb < NG);

    // ---- issue ALL 64 V loads first (FIFO: they drain before K prefetch) ----
    // lane needs V[kt+8g+j][16dt+lo16]; latency hides under QK^T + softmax
    float vtmp[64];
    if (wave_active) {
      const float* vp = Vb + (size_t)(kt + g * 8) * DH + lo16;
#pragma unroll
      for (int dt = 0; dt < 8; ++dt) {
#pragma unroll
        for (int j = 0; j < 8; ++j)
          vtmp[dt * 8 + j] = vp[(size_t)j * DH + dt * 16];
      }
    }

    // ---- prefetch next K tile into regs (block-uniform; overlaps compute) ----
    const int tn = (ti == 0) ? tstart : t + 1;
    if (tn <= t_hi) load_ktile(tn * TK);

    if (!wave_active) continue;   // barriers stay uniform

    // ---- QK^T: scores[4g+r][n*16+lo16], hi/lo split (3 mfma / 32-d chunk) ----
    f32x4 sc[2];
    __builtin_amdgcn_s_setprio(1);
#pragma unroll
    for (int n = 0; n < 2; ++n) {
      f32x4 acc = zero4;
      const int row = n * 16 + lo16;        // key within tile
      const int swz = (row & 7) << 4;
      const int rb  = row * 256;
#pragma unroll
      for (int c = 0; c < 4; ++c) {
        int byte = (rb + c * 64 + g * 16) ^ swz;
        bf16x8 kh = *(bf16x8*)((char*)khi + byte);
        bf16x8 kl = *(bf16x8*)((char*)klo + byte);
        acc = __builtin_amdgcn_mfma_f32_16x16x32_bf16(qhi[c], kl, acc, 0, 0, 0);
        acc = __builtin_amdgcn_mfma_f32_16x16x32_bf16(qlo[c], kh, acc, 0, 0, 0);
        acc = __builtin_amdgcn_mfma_f32_16x16x32_bf16(qhi[c], kh, acc, 0, 0, 0);
      }
      sc[n] = acc;
    }
    __builtin_amdgcn_s_setprio(0);

    // ---- mask (skip when tile fully inside every row's window) ----
    const bool full = (kt >= qb + 15 - HALF_W) && (kt + TK - 1 <= qb + HALF_W);
    if (!full) {
#pragma unroll
      for (int n = 0; n < 2; ++n) {
        const int j = kt + n * 16 + lo16;
#pragma unroll
        for (int r = 0; r < 4; ++r) {
          const int i = qb + g * 4 + r;
          const bool ok = ((unsigned)(j - i + HALF_W) <= 2u * HALF_W) ||
                          (j < NG) || (i < NG);
          if (!ok) sc[n][r] = -3.0e4f;
        }
      }
    }

    // ---- online softmax with defer-max (T13) ----
    f32x4 tmax;
#pragma unroll
    for (int r = 0; r < 4; ++r) tmax[r] = fmaxf(sc[0][r], sc[1][r]);
#pragma unroll
    for (int mo = 1; mo < 16; mo <<= 1) {
#pragma unroll
      for (int r = 0; r < 4; ++r)
        tmax[r] = fmaxf(tmax[r], __shfl_xor(tmax[r], mo, 64));
    }
    bool small = true;
#pragma unroll
    for (int r = 0; r < 4; ++r) small &= (tmax[r] <= mrow[r] + 8.0f);
    if (!__all(small)) {
      // full rescale path (rare after tile 0)
      float fr[4];
#pragma unroll
      for (int r = 0; r < 4; ++r) {
        float mnew = fmaxf(mrow[r], tmax[r]);
        fr[r]   = __expf(mrow[r] - mnew);
        mrow[r] = mnew;
        lrow[r] *= fr[r];
      }
#pragma unroll
      for (int dt = 0; dt < 8; ++dt) {
#pragma unroll
        for (int r = 0; r < 4; ++r) accO[dt][r] *= fr[r];
      }
    }
    float psum[4];
#pragma unroll
    for (int r = 0; r < 4; ++r) {
      float p0 = __expf(sc[0][r] - mrow[r]);   // bounded by e^8 under defer
      float p1 = __expf(sc[1][r] - mrow[r]);
      sc[0][r] = p0; sc[1][r] = p1;
      psum[r] = p0 + p1;
    }
#pragma unroll
    for (int mo = 1; mo < 16; mo <<= 1) {
#pragma unroll
      for (int r = 0; r < 4; ++r)
        psum[r] += __shfl_xor(psum[r], mo, 64);
    }
#pragma unroll
    for (int r = 0; r < 4; ++r) lrow[r] += psum[r];

    // ---- now convert V (single pipelined vmcnt drain, loads long in flight) ----
    bf16x8 vb[8];
#pragma unroll
    for (int dt = 0; dt < 8; ++dt) {
#pragma unroll
      for (int j = 0; j < 8; ++j)
        vb[dt][j] = (short)bfrn(vtmp[dt * 8 + j]);
    }

    // ---- P: C-layout -> LDS (swizzled) -> A-fragment ----
    unsigned short* pw = plds + w * (16 * TK);
#pragma unroll
    for (int n = 0; n < 2; ++n) {
#pragma unroll
      for (int r = 0; r < 4; ++r) {
        const int m_ = g * 4 + r;
        const int byte = (m_ * 64 + (n * 16 + lo16) * 2) ^ ((m_ & 7) << 4);
        *(unsigned short*)((char*)pw + byte) = bfrn(sc[n][r]);
      }
    }
    bf16x8 pa;
    {
      const int byte = (lo16 * 64 + g * 16) ^ ((lo16 & 7) << 4);
      pa = *(bf16x8*)((char*)pw + byte);
    }

    // ---- P·V ----
    __builtin_amdgcn_s_setprio(1);
#pragma unroll
    for (int dt = 0; dt < 8; ++dt)
      accO[dt] = __builtin_amdgcn_mfma_f32_16x16x32_bf16(pa, vb[dt], accO[dt], 0, 0, 0);
    __builtin_amdgcn_s_setprio(0);
  }

  // ---- epilogue: normalize + store (row-contiguous: full-line coalescing) ----
  float inv[4];
#pragma unroll
  for (int r = 0; r < 4; ++r) inv[r] = 1.0f / lrow[r];
#pragma unroll
  for (int r = 0; r < 4; ++r) {
    const int row = qb + g * 4 + r;
    float* op = Ob + (size_t)row * DH + lo16;
#pragma unroll
    for (int dt = 0; dt < 8; ++dt)
      op[dt * 16] = accO[dt][r] * inv[r];
  }
}

}  // namespace

extern "C" void kernel_launch(void* const* d_in, const int* in_sizes, int n_in,
                              void* d_out, int out_size, void* d_ws, size_t ws_size,
                              hipStream_t stream) {
  (void)in_sizes; (void)n_in; (void)out_size; (void)d_ws; (void)ws_size;
  const float* q = (const float*)d_in[0];
  const float* k = (const float*)d_in[1];
  const float* v = (const float*)d_in[2];
  float* o = (float*)d_out;
  dim3 grid(BH * (S_LEN / TQ));   // 1024 workgroups
  dim3 block(256);                // 4 waves
  gla_fwd<<<grid, block, 0, stream>>>(q, k, v, o);
}

// Round 5
// 411.622 us; speedup vs baseline: 2.5299x; 2.5299x over previous
//
#include <hip/hip_runtime.h>
#include <hip/hip_bf16.h>

namespace {

constexpr int S_LEN  = 2048;
constexpr int DH     = 128;
constexpr int NG     = 16;     // global tokens
constexpr int HALF_W = 256;    // WINDOW/2
constexpr int TQ     = 64;     // q rows per workgroup
constexpr int TK     = 32;     // keys per tile
constexpr int NT     = S_LEN / TK;  // 64
constexpr int BH     = 32;     // B*H

typedef __attribute__((ext_vector_type(8))) short bf16x8;
typedef __attribute__((ext_vector_type(8))) unsigned short u16x8;
typedef __attribute__((ext_vector_type(4))) float f32x4;

// hi = truncation to bf16 (1 op); residual returned for the lo part.
__device__ __forceinline__ unsigned short bfhi(float x, float& rem) {
  unsigned b = __builtin_bit_cast(unsigned, x);
  unsigned short h = (unsigned short)(b >> 16);
  rem = x - __builtin_bit_cast(float, (unsigned)h << 16);
  return h;
}
__device__ __forceinline__ unsigned short bftr(float x) {
  return (unsigned short)(__builtin_bit_cast(unsigned, x) >> 16);
}
// round-half-up to bf16 (2 ops; error <= 2^-9 rel) — for V and P
__device__ __forceinline__ unsigned short bfrn(float x) {
  return (unsigned short)((__builtin_bit_cast(unsigned, x) + 0x8000u) >> 16);
}

// ---------------- prepass: V [bh][s][d] fp32 -> VT [bh][d][s] bf16 ----------
// tile 64s x 64d per block, LDS transpose, 2048 blocks x 256 thr
__global__ __launch_bounds__(256)
void v_transpose(const float* __restrict__ V, unsigned short* __restrict__ VT)
{
  __shared__ unsigned short tile[64][66];   // 66: gcd(33,32)=1 -> spread banks

  const int b  = blockIdx.x;
  const int bh = b >> 6;
  const int s0 = ((b & 63) >> 1) * 64;
  const int d0 = (b & 1) * 64;
  const int tid = threadIdx.x;

  const float* Vb = V + (size_t)bh * S_LEN * DH;
#pragma unroll
  for (int it = 0; it < 4; ++it) {
    const int e   = it * 256 + tid;     // 0..1023
    const int sr  = e >> 4;             // 0..63
    const int dc  = (e & 15) * 4;       // 0..60
    float4 f = *(const float4*)(Vb + (size_t)(s0 + sr) * DH + d0 + dc);
    tile[sr][dc + 0] = bfrn(f.x);
    tile[sr][dc + 1] = bfrn(f.y);
    tile[sr][dc + 2] = bfrn(f.z);
    tile[sr][dc + 3] = bfrn(f.w);
  }
  __syncthreads();

  unsigned short* Tb = VT + (size_t)bh * DH * S_LEN;
  const int dr = tid >> 2;         // 0..63
  const int c  = tid & 3;          // 0..3 (16 s each)
  unsigned short* op = Tb + (size_t)(d0 + dr) * S_LEN + s0 + c * 16;
#pragma unroll
  for (int h = 0; h < 2; ++h) {
    u16x8 u;
#pragma unroll
    for (int j = 0; j < 8; ++j) u[j] = tile[c * 16 + h * 8 + j][dr];
    *(u16x8*)(op + h * 8) = u;
  }
}

// ---------------- main fused kernel ----------------------------------------
template <bool USE_VT>
__global__ __launch_bounds__(256, 3)
void gla_fwd(const float* __restrict__ Q, const float* __restrict__ K,
             const float* __restrict__ V, const unsigned short* __restrict__ VT,
             float* __restrict__ O)
{
  __shared__ unsigned short khi[TK * DH];       // 8 KB
  __shared__ unsigned short klo[TK * DH];       // 8 KB
  __shared__ unsigned short plds[4 * 16 * TK];  // 4 KB (1 KB per wave)

  const int tid  = threadIdx.x;
  const int w    = tid >> 6;
  const int l    = tid & 63;
  const int lo16 = l & 15;
  const int g    = l >> 4;

  // XCD-aware block swizzle (1024 % 8 == 0 -> bijective)
  const int nwg  = BH * (S_LEN / TQ);          // 1024
  const int cpx  = nwg >> 3;                   // 128
  const int bsw  = (blockIdx.x & 7) * cpx + (blockIdx.x >> 3);

  const int bh = bsw >> 5;            // 0..31
  const int i0 = (bsw & 31) * TQ;     // q row-tile base
  const int qb = i0 + w * 16;         // this wave's q base

  const size_t base = (size_t)bh * S_LEN * DH;
  const float* Qb = Q + base;
  const float* Kb = K + base;
  const float* Vb = V + base;
  const unsigned short* VTb = VT + base;   // [DH][S_LEN] bf16
  float*       Ob = O + base;

  // ---- Q fragments: scaled, hi/lo split. A-frag: lane holds Q[qb+lo16][32c+8g+j]
  bf16x8 qhi[4], qlo[4];
  {
    const float scale = 0.08838834764831845f;  // 1/sqrt(128)
    const float* qp = Qb + (size_t)(qb + lo16) * DH + g * 8;
#pragma unroll
    for (int c = 0; c < 4; ++c) {
      float4 a = *(const float4*)(qp + c * 32);
      float4 b = *(const float4*)(qp + c * 32 + 4);
      float xs[8] = {a.x, a.y, a.z, a.w, b.x, b.y, b.z, b.w};
#pragma unroll
      for (int j = 0; j < 8; ++j) {
        float x = xs[j] * scale, r;
        qhi[c][j] = (short)bfhi(x, r);
        qlo[c][j] = (short)bftr(r);
      }
    }
  }

  const f32x4 zero4 = {0.f, 0.f, 0.f, 0.f};
  f32x4 accO[8];
#pragma unroll
  for (int dt = 0; dt < 8; ++dt) accO[dt] = zero4;
  float mrow[4] = {-1e30f, -1e30f, -1e30f, -1e30f};
  float lrow[4] = {0.f, 0.f, 0.f, 0.f};

  int t_lo = (i0 - HALF_W) >> 5; if (t_lo < 0) t_lo = 0;
  int t_hi = (i0 + TQ - 1 + HALF_W) >> 5;
  if (i0 == 0) t_hi = NT - 1;               // global rows see everything
  if (t_hi > NT - 1) t_hi = NT - 1;
  const int tstart = (t_lo > 1) ? t_lo : 1; // tile 0 handled explicitly

  // ---- T14 async-STAGE: K tile for iteration ti is loaded to regs during ti-1
  float4 kreg[4];
  auto load_ktile = [&](int kt) {
#pragma unroll
    for (int i = 0; i < 4; ++i) {
      const int e   = (i * 256 + tid) * 4;
      const int row = e >> 7;
      const int d   = e & 127;
      kreg[i] = *(const float4*)(Kb + (size_t)(kt + row) * DH + d);
    }
  };
  load_ktile(0);   // prologue: tile 0

  for (int ti = 0;; ++ti) {
    const int t = (ti == 0) ? 0 : (tstart + ti - 1);
    if (ti > 0 && t > t_hi) break;
    const int kt = t * TK;

    __syncthreads();   // all waves done reading previous LDS tile
    // ---- cvt + write staged regs -> LDS bf16 hi/lo, XOR-swizzled ----
#pragma unroll
    for (int i = 0; i < 4; ++i) {
      const int e   = (i * 256 + tid) * 4;
      const int row = e >> 7;
      const int d   = e & 127;
      float4 f = kreg[i];
      ushort4 hv, lv;
      float r;
      hv.x = bfhi(f.x, r); lv.x = bftr(r);
      hv.y = bfhi(f.y, r); lv.y = bftr(r);
      hv.z = bfhi(f.z, r); lv.z = bftr(r);
      hv.w = bfhi(f.w, r); lv.w = bftr(r);
      const int byte = (row * 256 + d * 2) ^ ((row & 7) << 4);
      *(ushort4*)((char*)khi + byte) = hv;
      *(ushort4*)((char*)klo + byte) = lv;
    }
    __syncthreads();   // tile t visible to all waves

    // per-wave activity for this tile
    const bool wave_active =
        ((kt + TK - 1 >= qb - HALF_W) && (kt <= qb + 15 + HALF_W)) ||
        (t == 0) || (qb < NG);

    // ---- V fragments: issue early, consumed at PV (latency hides under QK+SM)
    // vb[dt] = VT[16dt+lo16][kt+8g .. +7]  — one 16 B load each
    bf16x8 vb[8];
    if (USE_VT) {
      if (wave_active) {
        const unsigned short* vp = VTb + (size_t)lo16 * S_LEN + kt + g * 8;
#pragma unroll
        for (int dt = 0; dt < 8; ++dt)
          vb[dt] = *(const bf16x8*)(vp + (size_t)dt * 16 * S_LEN);
      }
    }

    // ---- prefetch next K tile into regs (block-uniform; overlaps compute) ----
    const int tn = (ti == 0) ? tstart : t + 1;
    if (tn <= t_hi) load_ktile(tn * TK);

    if (!wave_active) continue;   // barriers stay uniform

    // ---- QK^T: scores[4g+r][n*16+lo16], hi/lo split (3 mfma / 32-d chunk) ----
    f32x4 sc[2];
    __builtin_amdgcn_s_setprio(1);
#pragma unroll
    for (int n = 0; n < 2; ++n) {
      f32x4 acc = zero4;
      const int row = n * 16 + lo16;        // key within tile
      const int swz = (row & 7) << 4;
      const int rb  = row * 256;
#pragma unroll
      for (int c = 0; c < 4; ++c) {
        int byte = (rb + c * 64 + g * 16) ^ swz;
        bf16x8 kh = *(bf16x8*)((char*)khi + byte);
        bf16x8 kl = *(bf16x8*)((char*)klo + byte);
        acc = __builtin_amdgcn_mfma_f32_16x16x32_bf16(qhi[c], kl, acc, 0, 0, 0);
        acc = __builtin_amdgcn_mfma_f32_16x16x32_bf16(qlo[c], kh, acc, 0, 0, 0);
        acc = __builtin_amdgcn_mfma_f32_16x16x32_bf16(qhi[c], kh, acc, 0, 0, 0);
      }
      sc[n] = acc;
    }
    __builtin_amdgcn_s_setprio(0);

    if (!USE_VT) {   // fallback: scalar global V loads (R3 path)
      const float* vp = Vb + (size_t)(kt + g * 8) * DH + lo16;
#pragma unroll
      for (int dt = 0; dt < 8; ++dt) {
        float tmp[8];
#pragma unroll
        for (int j = 0; j < 8; ++j) tmp[j] = vp[(size_t)j * DH + dt * 16];
#pragma unroll
        for (int j = 0; j < 8; ++j) vb[dt][j] = (short)bfrn(tmp[j]);
      }
    }

    // ---- mask (skip when tile fully inside every row's window) ----
    const bool full = (kt >= qb + 15 - HALF_W) && (kt + TK - 1 <= qb + HALF_W);
    if (!full) {
#pragma unroll
      for (int n = 0; n < 2; ++n) {
        const int j = kt + n * 16 + lo16;
#pragma unroll
        for (int r = 0; r < 4; ++r) {
          const int i = qb + g * 4 + r;
          const bool ok = ((unsigned)(j - i + HALF_W) <= 2u * HALF_W) ||
                          (j < NG) || (i < NG);
          if (!ok) sc[n][r] = -3.0e4f;
        }
      }
    }

    // ---- online softmax with defer-max (T13) ----
    f32x4 tmax;
#pragma unroll
    for (int r = 0; r < 4; ++r) tmax[r] = fmaxf(sc[0][r], sc[1][r]);
#pragma unroll
    for (int mo = 1; mo < 16; mo <<= 1) {
#pragma unroll
      for (int r = 0; r < 4; ++r)
        tmax[r] = fmaxf(tmax[r], __shfl_xor(tmax[r], mo, 64));
    }
    bool small = true;
#pragma unroll
    for (int r = 0; r < 4; ++r) small &= (tmax[r] <= mrow[r] + 8.0f);
    if (!__all(small)) {
      float fr[4];
#pragma unroll
      for (int r = 0; r < 4; ++r) {
        float mnew = fmaxf(mrow[r], tmax[r]);
        fr[r]   = __expf(mrow[r] - mnew);
        mrow[r] = mnew;
        lrow[r] *= fr[r];
      }
#pragma unroll
      for (int dt = 0; dt < 8; ++dt) {
#pragma unroll
        for (int r = 0; r < 4; ++r) accO[dt][r] *= fr[r];
      }
    }
    float psum[4];
#pragma unroll
    for (int r = 0; r < 4; ++r) {
      float p0 = __expf(sc[0][r] - mrow[r]);   // bounded by e^8 under defer
      float p1 = __expf(sc[1][r] - mrow[r]);
      sc[0][r] = p0; sc[1][r] = p1;
      psum[r] = p0 + p1;
    }
#pragma unroll
    for (int mo = 1; mo < 16; mo <<= 1) {
#pragma unroll
      for (int r = 0; r < 4; ++r)
        psum[r] += __shfl_xor(psum[r], mo, 64);
    }
#pragma unroll
    for (int r = 0; r < 4; ++r) lrow[r] += psum[r];

    // ---- P: C-layout -> LDS (swizzled) -> A-fragment ----
    unsigned short* pw = plds + w * (16 * TK);
#pragma unroll
    for (int n = 0; n < 2; ++n) {
#pragma unroll
      for (int r = 0; r < 4; ++r) {
        const int m_ = g * 4 + r;
        const int byte = (m_ * 64 + (n * 16 + lo16) * 2) ^ ((m_ & 7) << 4);
        *(unsigned short*)((char*)pw + byte) = bfrn(sc[n][r]);
      }
    }
    bf16x8 pa;
    {
      const int byte = (lo16 * 64 + g * 16) ^ ((lo16 & 7) << 4);
      pa = *(bf16x8*)((char*)pw + byte);
    }

    // ---- P·V ----
    __builtin_amdgcn_s_setprio(1);
#pragma unroll
    for (int dt = 0; dt < 8; ++dt)
      accO[dt] = __builtin_amdgcn_mfma_f32_16x16x32_bf16(pa, vb[dt], accO[dt], 0, 0, 0);
    __builtin_amdgcn_s_setprio(0);
  }

  // ---- epilogue: normalize + store (row-contiguous: full-line coalescing) ----
  float inv[4];
#pragma unroll
  for (int r = 0; r < 4; ++r) inv[r] = 1.0f / lrow[r];
#pragma unroll
  for (int r = 0; r < 4; ++r) {
    const int row = qb + g * 4 + r;
    float* op = Ob + (size_t)row * DH + lo16;
#pragma unroll
    for (int dt = 0; dt < 8; ++dt)
      op[dt * 16] = accO[dt][r] * inv[r];
  }
}

}  // namespace

extern "C" void kernel_launch(void* const* d_in, const int* in_sizes, int n_in,
                              void* d_out, int out_size, void* d_ws, size_t ws_size,
                              hipStream_t stream) {
  (void)in_sizes; (void)n_in; (void)out_size;
  const float* q = (const float*)d_in[0];
  const float* k = (const float*)d_in[1];
  const float* v = (const float*)d_in[2];
  float* o = (float*)d_out;

  const size_t vt_bytes = (size_t)BH * S_LEN * DH * sizeof(unsigned short); // 16 MB
  dim3 block(256);
  dim3 grid(BH * (S_LEN / TQ));   // 1024 workgroups

  if (ws_size >= vt_bytes) {
    unsigned short* vt = (unsigned short*)d_ws;
    v_transpose<<<dim3(BH * 64), block, 0, stream>>>(v, vt);
    gla_fwd<true><<<grid, block, 0, stream>>>(q, k, v, vt, o);
  } else {
    gla_fwd<false><<<grid, block, 0, stream>>>(q, k, v, nullptr, o);
  }
}

// Round 6
// 318.807 us; speedup vs baseline: 3.2665x; 1.2911x over previous
//
#include <hip/hip_runtime.h>
#include <hip/hip_bf16.h>

namespace {

constexpr int S_LEN  = 2048;
constexpr int DH     = 128;
constexpr int NG     = 16;     // global tokens
constexpr int HALF_W = 256;    // WINDOW/2
constexpr int TQ     = 64;     // q rows per main workgroup
constexpr int TK     = 32;     // keys per tile
constexpr int NT     = S_LEN / TK;  // 64
constexpr int BH     = 32;     // B*H
constexpr int NWG_MAIN = BH * (S_LEN / TQ);  // 1024
constexpr int PROW   = 40;     // padded plds row length in u16 (80 B, 16B-aligned)

typedef __attribute__((ext_vector_type(8))) short bf16x8;
typedef __attribute__((ext_vector_type(8))) unsigned short u16x8;
typedef __attribute__((ext_vector_type(4))) float f32x4;

__device__ __forceinline__ unsigned short bfhi(float x, float& rem) {
  unsigned b = __builtin_bit_cast(unsigned, x);
  unsigned short h = (unsigned short)(b >> 16);
  rem = x - __builtin_bit_cast(float, (unsigned)h << 16);
  return h;
}
__device__ __forceinline__ unsigned short bftr(float x) {
  return (unsigned short)(__builtin_bit_cast(unsigned, x) >> 16);
}
__device__ __forceinline__ unsigned short bfrn(float x) {
  return (unsigned short)((__builtin_bit_cast(unsigned, x) + 0x8000u) >> 16);
}

// ---------------- prepass: V [bh][s][d] fp32 -> VT [bh][d][s] bf16 ----------
__global__ __launch_bounds__(256)
void v_transpose(const float* __restrict__ V, unsigned short* __restrict__ VT)
{
  __shared__ unsigned short tile[64][66];

  const int b  = blockIdx.x;
  const int bh = b >> 6;
  const int s0 = ((b & 63) >> 1) * 64;
  const int d0 = (b & 1) * 64;
  const int tid = threadIdx.x;

  const float* Vb = V + (size_t)bh * S_LEN * DH;
#pragma unroll
  for (int it = 0; it < 4; ++it) {
    const int e   = it * 256 + tid;
    const int sr  = e >> 4;
    const int dc  = (e & 15) * 4;
    float4 f = *(const float4*)(Vb + (size_t)(s0 + sr) * DH + d0 + dc);
    tile[sr][dc + 0] = bfrn(f.x);
    tile[sr][dc + 1] = bfrn(f.y);
    tile[sr][dc + 2] = bfrn(f.z);
    tile[sr][dc + 3] = bfrn(f.w);
  }
  __syncthreads();

  unsigned short* Tb = VT + (size_t)bh * DH * S_LEN;
  const int dr = tid >> 2;
  const int c  = tid & 3;
  unsigned short* op = Tb + (size_t)(d0 + dr) * S_LEN + s0 + c * 16;
#pragma unroll
  for (int h = 0; h < 2; ++h) {
    u16x8 u;
#pragma unroll
    for (int j = 0; j < 8; ++j) u[j] = tile[c * 16 + h * 8 + j][dr];
    *(u16x8*)(op + h * 8) = u;
  }
}

// ---------------- per-tile worker (swapped operands, no barriers) -----------
// S^T = mfma(A=K, B=Q): lane holds S[key=16n+g*4+r][qrow=lo16].
// O^T = mfma(A=V^T, B=P^T): lane holds O[d=16dt+g*4+r][qrow=lo16].
template<bool MASKED, bool USE_VT>
__device__ __forceinline__ void process_tile(
    int kt, int qb, int lo16, int g,
    const float* __restrict__ Kb, const unsigned short* __restrict__ VTb,
    const float* __restrict__ Vb,
    const bf16x8 (&qhi)[4], const bf16x8 (&qlo)[4],
    char* __restrict__ pw,                     // wave-private plds (bytes)
    float& mrow, float& lrow, f32x4 (&accO)[8])
{
  const int qrow = qb + lo16;

  // ---- issue K loads (A-frag: rows = keys, contiguous 32B per (n,c)) ----
  f32x4 kr[2][4][2];
#pragma unroll
  for (int n = 0; n < 2; ++n) {
    const float* kp = Kb + (size_t)(kt + n * 16 + lo16) * DH + g * 8;
#pragma unroll
    for (int c = 0; c < 4; ++c) {
      kr[n][c][0] = *(const f32x4*)(kp + c * 32);
      kr[n][c][1] = *(const f32x4*)(kp + c * 32 + 4);
    }
  }
  // ---- issue V loads (A-frag of V^T: 16B contiguous from VT) ----
  bf16x8 vb[8];
  if (USE_VT) {
    const unsigned short* vp = VTb + (size_t)lo16 * S_LEN + kt + g * 8;
#pragma unroll
    for (int dt = 0; dt < 8; ++dt)
      vb[dt] = *(const bf16x8*)(vp + (size_t)dt * 16 * S_LEN);
  }

  // ---- cvt K to bf16 hi/lo and run QK^T per 16-key half ----
  const f32x4 zero4 = {0.f, 0.f, 0.f, 0.f};
  f32x4 sc[2];
#pragma unroll
  for (int n = 0; n < 2; ++n) {
    bf16x8 khi[4], klo[4];
#pragma unroll
    for (int c = 0; c < 4; ++c) {
#pragma unroll
      for (int j = 0; j < 8; ++j) {
        float x = (j < 4) ? kr[n][c][0][j] : kr[n][c][1][j - 4];
        float rr;
        khi[c][j] = (short)bfhi(x, rr);
        klo[c][j] = (short)bftr(rr);
      }
    }
    f32x4 acc = zero4;
#pragma unroll
    for (int c = 0; c < 4; ++c) {
      acc = __builtin_amdgcn_mfma_f32_16x16x32_bf16(klo[c], qhi[c], acc, 0, 0, 0);
      acc = __builtin_amdgcn_mfma_f32_16x16x32_bf16(khi[c], qlo[c], acc, 0, 0, 0);
      acc = __builtin_amdgcn_mfma_f32_16x16x32_bf16(khi[c], qhi[c], acc, 0, 0, 0);
    }
    sc[n] = acc;
  }

  if (!USE_VT) {   // fallback: scalar V gather (no VT workspace)
#pragma unroll
    for (int dt = 0; dt < 8; ++dt) {
      const float* vp0 = Vb + (size_t)(kt + g * 8) * DH + dt * 16 + lo16;
      float t0[8];
#pragma unroll
      for (int j = 0; j < 8; ++j) t0[j] = vp0[(size_t)j * DH];
#pragma unroll
      for (int j = 0; j < 8; ++j) vb[dt][j] = (short)bfrn(t0[j]);
    }
  }

  // ---- mask (main path only; rows here always >= NG) ----
  if (MASKED) {
    const bool full = (kt >= qb + 15 - HALF_W) && (kt + TK - 1 <= qb + HALF_W);
    if (!full) {
#pragma unroll
      for (int n = 0; n < 2; ++n) {
#pragma unroll
        for (int r = 0; r < 4; ++r) {
          const int j = kt + n * 16 + g * 4 + r;
          const bool ok = ((unsigned)(j - qrow + HALF_W) <= 2u * HALF_W) || (j < NG);
          if (!ok) sc[n][r] = -3.0e4f;
        }
      }
    }
  }

  // ---- online softmax (q-row is lane-local: 2 shuffles total) ----
  float pmax = fmaxf(fmaxf(fmaxf(sc[0][0], sc[0][1]), fmaxf(sc[0][2], sc[0][3])),
                     fmaxf(fmaxf(sc[1][0], sc[1][1]), fmaxf(sc[1][2], sc[1][3])));
  pmax = fmaxf(pmax, __shfl_xor(pmax, 16, 64));
  pmax = fmaxf(pmax, __shfl_xor(pmax, 32, 64));
  if (!__all(pmax <= mrow + 8.0f)) {          // defer-max (T13)
    const float mnew = fmaxf(mrow, pmax);
    const float fr = __expf(mrow - mnew);
    lrow *= fr;
#pragma unroll
    for (int dt = 0; dt < 8; ++dt) accO[dt] *= fr;
    mrow = mnew;
  }
  float ps = 0.f;
#pragma unroll
  for (int n = 0; n < 2; ++n) {
#pragma unroll
    for (int r = 0; r < 4; ++r) {
      sc[n][r] = __expf(sc[n][r] - mrow);
      ps += sc[n][r];
    }
  }
  ps += __shfl_xor(ps, 16, 64);
  ps += __shfl_xor(ps, 32, 64);
  lrow += ps;

  // ---- P^T -> wave-private LDS -> B-frag (no barrier; same-wave lgkmcnt) ----
#pragma unroll
  for (int n = 0; n < 2; ++n) {
#pragma unroll
    for (int pr = 0; pr < 2; ++pr) {
      const unsigned pv = (unsigned)bfrn(sc[n][2 * pr]) |
                          ((unsigned)bfrn(sc[n][2 * pr + 1]) << 16);
      const int kpos = 16 * n + g * 4 + 2 * pr;
      const int slot = kpos >> 3;
      const int byte = lo16 * (PROW * 2) + ((slot ^ (lo16 & 3)) << 4) +
                       ((kpos & 7) << 1);
      *(unsigned*)(pw + byte) = pv;
    }
  }
  bf16x8 pa;
  {
    const int byte = lo16 * (PROW * 2) + ((g ^ (lo16 & 3)) << 4);
    pa = *(const bf16x8*)(pw + byte);
  }

  // ---- P·V (one k=32 MFMA per 16-d block) ----
#pragma unroll
  for (int dt = 0; dt < 8; ++dt)
    accO[dt] = __builtin_amdgcn_mfma_f32_16x16x32_bf16(vb[dt], pa, accO[dt], 0, 0, 0);
}

// ---------------- fused kernel: 1024 main blocks + 32 global-row blocks -----
template<bool USE_VT>
__global__ __launch_bounds__(256, 2)
void gla_fwd(const float* __restrict__ Q, const float* __restrict__ K,
             const float* __restrict__ V, const unsigned short* __restrict__ VT,
             float* __restrict__ O)
{
  __shared__ unsigned short plds[4 * 16 * PROW];   // 5 KB, wave-private slices
  __shared__ float macc[4][DH][16];                // 32 KB (global path only)
  __shared__ float mml[4][16][2];

  const int tid  = threadIdx.x;
  const int w    = tid >> 6;
  const int l    = tid & 63;
  const int lo16 = l & 15;
  const int g    = l >> 4;
  char* pw = (char*)(plds + w * (16 * PROW));

  const float scale = 0.08838834764831845f;  // 1/sqrt(128)
  const f32x4 zero4 = {0.f, 0.f, 0.f, 0.f};

  if (blockIdx.x < NWG_MAIN) {
    // =================== main path: window + global-cols ===================
    const int cpx = NWG_MAIN >> 3;
    const int bsw = ((int)blockIdx.x & 7) * cpx + ((int)blockIdx.x >> 3);
    const int bh  = bsw >> 5;
    const int i0  = (bsw & 31) * TQ;
    const int qb  = i0 + w * 16;
    if (qb == 0) return;          // rows 0..15 owned by the global path

    const size_t base = (size_t)bh * S_LEN * DH;
    const float* Qb = Q + base;
    const float* Kb = K + base;
    const float* Vb = V + base;
    const unsigned short* VTb = VT + base;
    float* Ob = O + base;

    bf16x8 qhi[4], qlo[4];
    {
      const float* qp = Qb + (size_t)(qb + lo16) * DH + g * 8;
#pragma unroll
      for (int c = 0; c < 4; ++c) {
        f32x4 a = *(const f32x4*)(qp + c * 32);
        f32x4 b = *(const f32x4*)(qp + c * 32 + 4);
#pragma unroll
        for (int j = 0; j < 8; ++j) {
          float x = ((j < 4) ? a[j] : b[j - 4]) * scale, rr;
          qhi[c][j] = (short)bfhi(x, rr);
          qlo[c][j] = (short)bftr(rr);
        }
      }
    }

    f32x4 accO[8];
#pragma unroll
    for (int dt = 0; dt < 8; ++dt) accO[dt] = zero4;
    float mrow = -1e30f, lrow = 0.f;

    int t_lo = (i0 - HALF_W) >> 5; if (t_lo < 0) t_lo = 0;
    int t_hi = (i0 + TQ - 1 + HALF_W) >> 5; if (t_hi > NT - 1) t_hi = NT - 1;
    const int tstart = (t_lo > 1) ? t_lo : 1;

    process_tile<true, USE_VT>(0, qb, lo16, g, Kb, VTb, Vb, qhi, qlo, pw,
                               mrow, lrow, accO);
    for (int t = tstart; t <= t_hi; ++t)
      process_tile<true, USE_VT>(t * TK, qb, lo16, g, Kb, VTb, Vb, qhi, qlo, pw,
                                 mrow, lrow, accO);

    const float inv = 1.0f / lrow;
    float* op = Ob + (size_t)(qb + lo16) * DH;
#pragma unroll
    for (int dt = 0; dt < 8; ++dt) {
      f32x4 o = accO[dt] * inv;
      *(f32x4*)(op + dt * 16 + g * 4) = o;
    }
  } else {
    // =================== global-rows path: rows 0..15, all keys ============
    const int bh = (int)blockIdx.x - NWG_MAIN;
    const size_t base = (size_t)bh * S_LEN * DH;
    const float* Qb = Q + base;
    const float* Kb = K + base;
    const float* Vb = V + base;
    const unsigned short* VTb = VT + base;
    float* Ob = O + base;

    bf16x8 qhi[4], qlo[4];
    {
      const float* qp = Qb + (size_t)lo16 * DH + g * 8;
#pragma unroll
      for (int c = 0; c < 4; ++c) {
        f32x4 a = *(const f32x4*)(qp + c * 32);
        f32x4 b = *(const f32x4*)(qp + c * 32 + 4);
#pragma unroll
        for (int j = 0; j < 8; ++j) {
          float x = ((j < 4) ? a[j] : b[j - 4]) * scale, rr;
          qhi[c][j] = (short)bfhi(x, rr);
          qlo[c][j] = (short)bftr(rr);
        }
      }
    }

    f32x4 accO[8];
#pragma unroll
    for (int dt = 0; dt < 8; ++dt) accO[dt] = zero4;
    float mrow = -1e30f, lrow = 0.f;

    // wave w handles tiles w, w+4, ..., w+60 (16 tiles); no mask (rows < NG)
    for (int i = 0; i < 16; ++i)
      process_tile<false, USE_VT>((w + 4 * i) * TK, 0, lo16, g, Kb, VTb, Vb,
                                  qhi, qlo, pw, mrow, lrow, accO);

    // ---- write per-wave partials, merge across the 4 waves ----
#pragma unroll
    for (int dt = 0; dt < 8; ++dt) {
#pragma unroll
      for (int r = 0; r < 4; ++r)
        macc[w][dt * 16 + g * 4 + r][lo16] = accO[dt][r];
    }
    if (l < 16) { mml[w][l][0] = mrow; mml[w][l][1] = lrow; }
    __syncthreads();

    const int row = tid >> 4;          // 0..15
    const int d0  = (tid & 15) * 8;
    float mm[4], sw[4];
    float mstar = -1e30f;
#pragma unroll
    for (int w2 = 0; w2 < 4; ++w2) { mm[w2] = mml[w2][row][0]; mstar = fmaxf(mstar, mm[w2]); }
    float den = 0.f;
#pragma unroll
    for (int w2 = 0; w2 < 4; ++w2) { sw[w2] = __expf(mm[w2] - mstar); den += sw[w2] * mml[w2][row][1]; }
    const float inv = 1.0f / den;
    float outv[8];
#pragma unroll
    for (int dd = 0; dd < 8; ++dd) {
      float num = 0.f;
#pragma unroll
      for (int w2 = 0; w2 < 4; ++w2) num += sw[w2] * macc[w2][d0 + dd][row];
      outv[dd] = num * inv;
    }
    float* op = Ob + (size_t)row * DH + d0;
    f32x4 o0 = {outv[0], outv[1], outv[2], outv[3]};
    f32x4 o1 = {outv[4], outv[5], outv[6], outv[7]};
    *(f32x4*)op = o0;
    *(f32x4*)(op + 4) = o1;
  }
}

}  // namespace

extern "C" void kernel_launch(void* const* d_in, const int* in_sizes, int n_in,
                              void* d_out, int out_size, void* d_ws, size_t ws_size,
                              hipStream_t stream) {
  (void)in_sizes; (void)n_in; (void)out_size;
  const float* q = (const float*)d_in[0];
  const float* k = (const float*)d_in[1];
  const float* v = (const float*)d_in[2];
  float* o = (float*)d_out;

  const size_t vt_bytes = (size_t)BH * S_LEN * DH * sizeof(unsigned short); // 16 MB
  dim3 block(256);
  dim3 grid(NWG_MAIN + BH);   // 1024 main + 32 global-row blocks

  if (ws_size >= vt_bytes) {
    unsigned short* vt = (unsigned short*)d_ws;
    v_transpose<<<dim3(BH * 64), block, 0, stream>>>(v, vt);
    gla_fwd<true><<<grid, block, 0, stream>>>(q, k, v, vt, o);
  } else {
    gla_fwd<false><<<grid, block, 0, stream>>>(q, k, v, nullptr, o);
  }
}